// Round 19
// baseline (299.249 us; speedup 1.0000x reference)
//
#include <hip/hip_runtime.h>
#include <hip/hip_bf16.h>

#define B_ 2
#define T_ 2048
#define C_ 1024
#define H_ 16
#define D_ 64
#define BT_ (B_*T_)
#define N3_ (3*C_)
#define NKT_ (T_/64)     // 32 k-tiles of 64
#define NQT_ (T_/128)    // 16 q-tiles of 128

typedef float f32x4 __attribute__((ext_vector_type(4)));
typedef unsigned short u16x4 __attribute__((ext_vector_type(4)));
typedef unsigned short u16x8 __attribute__((ext_vector_type(8)));
typedef __bf16 bf16x8 __attribute__((ext_vector_type(8)));

// MFMA via intrinsic ONLY (raw inline-asm MFMA lacks compiler hazard waits ->
// schedule-dependent corruption, proven rounds 2/3/4/7/8 vs 9).
__device__ __forceinline__ f32x4 mfma16(u16x8 a, u16x8 b, f32x4 c) {
  union Cvt { u16x8 u; bf16x8 h; };
  Cvt ua, ub; ua.u = a; ub.u = b;
  return __builtin_amdgcn_mfma_f32_16x16x32_bf16(ua.h, ub.h, c, 0, 0, 0);
}

// raw v_exp_f32 (2^x).
__device__ __forceinline__ float exp2_fast(float x) {
  return __builtin_amdgcn_exp2f(x);
}

__device__ __forceinline__ unsigned short f2bf(float f) {
  union { float f; unsigned u; } v; v.f = f;
  unsigned r = v.u + 0x7FFFu + ((v.u >> 16) & 1u);
  return (unsigned short)(r >> 16);
}

__device__ __forceinline__ float bf2f(unsigned short u) {
  union { unsigned u; float f; } v; v.u = ((unsigned)u) << 16;
  return v.f;
}

// Non-temporal f32x4 store: att is a 537 MB write-once stream; bypass L2
// write-allocate so K/V working set stays resident (round 18: -27 us).
__device__ __forceinline__ void nt_store4(float* p, f32x4 v) {
  __builtin_nontemporal_store(v, (f32x4*)p);
}

__device__ __forceinline__ void gload_lds16(const unsigned short* g, unsigned short* l) {
  __builtin_amdgcn_global_load_lds(
      (const __attribute__((address_space(1))) unsigned int*)g,
      (__attribute__((address_space(3))) unsigned int*)l, 16, 0, 0);
}

// ---------------- transpose fp32 W[K][N] -> bf16 WT[N][K] ----------------
__global__ __launch_bounds__(256) void transpose_to_bf16T(
    const float* __restrict__ W, unsigned short* __restrict__ WT, int K, int N) {
  __shared__ float tile[32][33];
  int n0 = blockIdx.x * 32, k0 = blockIdx.y * 32;
  int tx = threadIdx.x & 31, ty = threadIdx.x >> 5;  // 32 x 8
#pragma unroll
  for (int i = 0; i < 4; ++i)
    tile[ty + i * 8][tx] = W[(size_t)(k0 + ty + i * 8) * N + n0 + tx];
  __syncthreads();
#pragma unroll
  for (int i = 0; i < 4; ++i)
    WT[(size_t)(n0 + ty + i * 8) * K + k0 + tx] = f2bf(tile[tx][ty + i * 8]);
}

// ---------------- convert x fp32 -> bf16 ----------------
__global__ __launch_bounds__(256) void convert_x(const float* __restrict__ x,
                                                 unsigned short* __restrict__ xb) {
  int i = (blockIdx.x * 256 + threadIdx.x) * 8;
  f32x4 a = *(const f32x4*)(x + i);
  f32x4 b = *(const f32x4*)(x + i + 4);
  u16x8 o;
  o[0]=f2bf(a[0]); o[1]=f2bf(a[1]); o[2]=f2bf(a[2]); o[3]=f2bf(a[3]);
  o[4]=f2bf(b[0]); o[5]=f2bf(b[1]); o[6]=f2bf(b[2]); o[7]=f2bf(b[3]);
  *(u16x8*)(xb + i) = o;
}

// ---------------- GEMM1: qkv = xb @ WaT^T + b_attn -> bf16 Q/K (row) + V^T ----------------
__global__ __launch_bounds__(256) void gemm_qkv(
    const unsigned short* __restrict__ xb, const unsigned short* __restrict__ WaT,
    const float* __restrict__ bias, unsigned short* __restrict__ qkv) {
  __shared__ __attribute__((aligned(16))) unsigned short As[128 * 32];
  __shared__ __attribute__((aligned(16))) unsigned short Bs[128 * 32];
  int n0 = blockIdx.x * 128;
  int m0 = blockIdx.y * 128;
  int tid = threadIdx.x;
  int lane = tid & 63, wid = tid >> 6;
  int wm = wid >> 1, wn = wid & 1;
  int l15 = lane & 15, l4 = lane >> 4;
  int srow = lane >> 2, scol = (lane & 3) << 3;

  f32x4 acc[4][4];
#pragma unroll
  for (int i = 0; i < 4; ++i)
#pragma unroll
    for (int j = 0; j < 4; ++j) acc[i][j] = (f32x4){0.f, 0.f, 0.f, 0.f};

  for (int ks = 0; ks < C_ / 32; ++ks) {
#pragma unroll
    for (int j = 0; j < 2; ++j) {
      int row = wid * 16 + j * 64 + srow;
      gload_lds16(xb + (size_t)(m0 + row) * C_ + ks * 32 + scol,
                  &As[(wid * 16 + j * 64) * 32]);
      gload_lds16(WaT + (size_t)(n0 + row) * C_ + ks * 32 + scol,
                  &Bs[(wid * 16 + j * 64) * 32]);
    }
    __syncthreads();
    u16x8 af[4], bfr[4];
#pragma unroll
    for (int mi = 0; mi < 4; ++mi)
      af[mi] = *(const u16x8*)&As[(wm * 64 + mi * 16 + l15) * 32 + l4 * 8];
#pragma unroll
    for (int ni = 0; ni < 4; ++ni)
      bfr[ni] = *(const u16x8*)&Bs[(wn * 64 + ni * 16 + l15) * 32 + l4 * 8];
#pragma unroll
    for (int mi = 0; mi < 4; ++mi)
#pragma unroll
      for (int ni = 0; ni < 4; ++ni) acc[mi][ni] = mfma16(af[mi], bfr[ni], acc[mi][ni]);
    __syncthreads();
  }

  if (n0 < 2 * C_) {
    // Q/K: [sect][b][h][t][d]; Q pre-scaled by 0.125*log2e (exp2 softmax)
    float qscale = (n0 < C_) ? 0.125f * 1.44269504f : 1.0f;
#pragma unroll
    for (int mi = 0; mi < 4; ++mi)
#pragma unroll
      for (int ni = 0; ni < 4; ++ni)
#pragma unroll
        for (int rr = 0; rr < 4; ++rr) {
          int m = m0 + wm * 64 + mi * 16 + l4 * 4 + rr;
          int n = n0 + wn * 64 + ni * 16 + l15;
          float v = (acc[mi][ni][rr] + bias[n]) * qscale;
          int b = m >> 11, tok = m & (T_ - 1);
          int sect = n >> 10, h = (n >> 6) & 15, d = n & 63;
          size_t idx = ((((size_t)sect * B_ + b) * H_ + h) * T_ + tok) * D_ + d;
          qkv[idx] = f2bf(v);
        }
  } else {
    // V -> [b][h][d][t]: 4 consecutive tokens per lane -> u16x4 direct store.
    unsigned short* vbase = qkv + (size_t)2 * B_ * H_ * T_ * D_;
    int m_b = m0 >> 11;
#pragma unroll
    for (int mi = 0; mi < 4; ++mi) {
      int m = m0 + wm * 64 + mi * 16 + l4 * 4;   // first of 4 consecutive tokens
      int tok = m & (T_ - 1);
#pragma unroll
      for (int ni = 0; ni < 4; ++ni) {
        int n = n0 + wn * 64 + ni * 16 + l15;
        float bi = bias[n];
        int h = (n >> 6) & 15, d = n & 63;
        u16x4 val;
        val[0] = f2bf(acc[mi][ni][0] + bi);
        val[1] = f2bf(acc[mi][ni][1] + bi);
        val[2] = f2bf(acc[mi][ni][2] + bi);
        val[3] = f2bf(acc[mi][ni][3] + bi);
        *(u16x4*)&vbase[(((size_t)m_b * H_ + h) * D_ + d) * T_ + tok] = val;
      }
    }
  }
}

// ---------------- fused causal attention, QBLK=128 (8 waves), NT att stores ----------------
// Zero-fill issued BEFORE pass 1: independent NT stores drain under pass-1 compute.
__global__ __launch_bounds__(512) void attn_kernel(
    const unsigned short* __restrict__ qkv, float* __restrict__ att,
    unsigned short* __restrict__ Y) {
  int idx = blockIdx.x;
  int qt = NQT_ - 1 - (idx >> 5);   // descending: big blocks dispatch first
  int hb = idx & 31;
  int h = hb & 15;
  int b = hb >> 4;
  int q0 = qt * 128;
  int nkt = 2 * qt + 2;             // k-tiles covering rows q0..q0+127
  int tid = threadIdx.x, lane = tid & 63, wid = tid >> 6;   // wid 0..7
  int l15 = lane & 15, l4 = lane >> 4;
  int rowbase = q0 + wid * 16;

  const unsigned short* Q = qkv + (((size_t)(0 * B_ + b) * H_ + h) * T_) * D_;
  const unsigned short* K = qkv + (((size_t)(1 * B_ + b) * H_ + h) * T_) * D_;
  const unsigned short* VtG = qkv + (size_t)2 * B_ * H_ * T_ * D_ +
                              (((size_t)b * H_ + h) * D_) * T_;
  float* attbase = att + ((size_t)(b * H_ + h) * T_) * T_;

  __shared__ __attribute__((aligned(16))) unsigned short Ps[2][128][72];
  __shared__ __attribute__((aligned(16))) unsigned short Vt[2][64][72];

  int myrow[4];
#pragma unroll
  for (int rr = 0; rr < 4; ++rr) myrow[rr] = rowbase + l4 * 4 + rr;

  // ---- zero-fill upper tiles FIRST: fire-and-forget NT stores overlap pass 1 ----
  f32x4 z = (f32x4){0.f, 0.f, 0.f, 0.f};
  for (int kt = nkt; kt < NKT_; ++kt) {
    int k0 = kt * 64;
#pragma unroll
    for (int rr = 0; rr < 4; ++rr)
      nt_store4(&attbase[(size_t)myrow[rr] * T_ + k0 + l15 * 4], z);
  }

  // Q fragments (this wave owns rows rowbase .. rowbase+15)
  u16x8 qf[2];
#pragma unroll
  for (int c = 0; c < 2; ++c)
    qf[c] = *(const u16x8*)(Q + (size_t)(rowbase + l15) * D_ + c * 32 + l4 * 8);

  // ---- pass 1: per-lane partial row sums ----
  float esum[4] = {0.f, 0.f, 0.f, 0.f};
  for (int kt = 0; kt < nkt; ++kt) {
    int k0 = kt * 64;
    if (k0 > rowbase + 15) continue;  // fully masked for this wave (uniform)
    f32x4 s[4];
#pragma unroll
    for (int g = 0; g < 4; ++g) s[g] = (f32x4){0.f, 0.f, 0.f, 0.f};
#pragma unroll
    for (int g = 0; g < 4; ++g)
#pragma unroll
      for (int c = 0; c < 2; ++c) {
        u16x8 kf = *(const u16x8*)(K + (size_t)(k0 + g * 16 + l15) * D_ + c * 32 + l4 * 8);
        s[g] = mfma16(qf[c], kf, s[g]);
      }
    if (k0 + 63 <= rowbase) {  // fully visible (uniform)
#pragma unroll
      for (int g = 0; g < 4; ++g)
#pragma unroll
        for (int rr = 0; rr < 4; ++rr) esum[rr] += exp2_fast(s[g][rr]);
    } else {                   // diagonal
#pragma unroll
      for (int g = 0; g < 4; ++g) {
        int col = k0 + g * 16 + l15;
#pragma unroll
        for (int rr = 0; rr < 4; ++rr)
          esum[rr] += (col > myrow[rr]) ? 0.f : exp2_fast(s[g][rr]);
      }
    }
  }
  float inv_l[4];
#pragma unroll
  for (int rr = 0; rr < 4; ++rr) {
    float e = esum[rr];
    e += __shfl_xor(e, 1);
    e += __shfl_xor(e, 2);
    e += __shfl_xor(e, 4);
    e += __shfl_xor(e, 8);
    inv_l[rr] = 1.f / e;
  }

  // ---- pass 2: accumulate PV; att written NT from Ps; 1 barrier/tile via dbuf ----
  f32x4 yacc[4];
#pragma unroll
  for (int g = 0; g < 4; ++g) yacc[g] = (f32x4){0.f, 0.f, 0.f, 0.f};

  for (int kt = 0; kt < nkt; ++kt) {
    int k0 = kt * 64;
    int p = kt & 1;
    bool wave_masked = (k0 > rowbase + 15);
    // stage V^T tile into buf p (512 threads x u16x8 = 8 KB tile)
    {
      int dd = tid >> 3;
      int kq = (tid & 7) * 8;
      *(u16x8*)&Vt[p][dd][kq] = *(const u16x8*)(VtG + (size_t)dd * T_ + k0 + kq);
    }
    if (wave_masked) {
      // all p = 0 for this wave's rows: zero Ps, att zeros via readback
#pragma unroll
      for (int g = 0; g < 4; ++g)
#pragma unroll
        for (int rr = 0; rr < 4; ++rr)
          Ps[p][wid * 16 + l4 * 4 + rr][g * 16 + l15] = 0;
    } else {
      f32x4 s[4];
#pragma unroll
      for (int g = 0; g < 4; ++g) s[g] = (f32x4){0.f, 0.f, 0.f, 0.f};
#pragma unroll
      for (int g = 0; g < 4; ++g)
#pragma unroll
        for (int c = 0; c < 2; ++c) {
          u16x8 kf = *(const u16x8*)(K + (size_t)(k0 + g * 16 + l15) * D_ + c * 32 + l4 * 8);
          s[g] = mfma16(qf[c], kf, s[g]);
        }
      if (k0 + 63 <= rowbase) {
#pragma unroll
        for (int g = 0; g < 4; ++g)
#pragma unroll
          for (int rr = 0; rr < 4; ++rr)
            Ps[p][wid * 16 + l4 * 4 + rr][g * 16 + l15] =
                f2bf(exp2_fast(s[g][rr]) * inv_l[rr]);
      } else {
#pragma unroll
        for (int g = 0; g < 4; ++g) {
          int col = k0 + g * 16 + l15;
#pragma unroll
          for (int rr = 0; rr < 4; ++rr) {
            float pv = (col > myrow[rr]) ? 0.f : exp2_fast(s[g][rr]) * inv_l[rr];
            Ps[p][wid * 16 + l4 * 4 + rr][g * 16 + l15] = f2bf(pv);
          }
        }
      }
    }
    // att write: read own-wave Ps rows back vectorized; NT store (streamed).
    {
      int cc = l15 * 4;
#pragma unroll
      for (int jj = 0; jj < 4; ++jj) {
        int rrow = wid * 16 + jj * 4 + l4;
        const unsigned short* ps = &Ps[p][rrow][cc];
        f32x4 o;
        o[0] = bf2f(ps[0]); o[1] = bf2f(ps[1]);
        o[2] = bf2f(ps[2]); o[3] = bf2f(ps[3]);
        nt_store4(&attbase[(size_t)(q0 + rrow) * T_ + k0 + cc], o);
      }
    }
    __syncthreads();  // buf p fully written by all waves
    // PV from buf p (skip when this wave's P-rows are all zero)
    if (!wave_masked) {
#pragma unroll
      for (int c = 0; c < 2; ++c) {
        u16x8 pf = *(const u16x8*)&Ps[p][wid * 16 + l15][c * 32 + l4 * 8];
#pragma unroll
        for (int g = 0; g < 4; ++g) {
          u16x8 vf = *(const u16x8*)&Vt[p][g * 16 + l15][c * 32 + l4 * 8];
          yacc[g] = mfma16(pf, vf, yacc[g]);
        }
      }
    }
  }

  // write Y bf16 [BT][C]
#pragma unroll
  for (int g = 0; g < 4; ++g)
#pragma unroll
    for (int rr = 0; rr < 4; ++rr)
      Y[(size_t)(b * T_ + myrow[rr]) * C_ + h * D_ + g * 16 + l15] = f2bf(yacc[g][rr]);
}

// ---------------- GEMM2: out = Y @ W_proj + b_proj (fp32 out, NT) ----------------
__global__ __launch_bounds__(256) void gemm_proj(
    const unsigned short* __restrict__ Y, const unsigned short* __restrict__ WpT,
    const float* __restrict__ bias, float* __restrict__ out) {
  __shared__ __attribute__((aligned(16))) unsigned short As[128 * 32];
  __shared__ __attribute__((aligned(16))) unsigned short Bs[128 * 32];
  int n0 = blockIdx.x * 128;
  int m0 = blockIdx.y * 128;
  int tid = threadIdx.x;
  int lane = tid & 63, wid = tid >> 6;
  int wm = wid >> 1, wn = wid & 1;
  int l15 = lane & 15, l4 = lane >> 4;
  int srow = lane >> 2, scol = (lane & 3) << 3;

  f32x4 acc[4][4];
#pragma unroll
  for (int i = 0; i < 4; ++i)
#pragma unroll
    for (int j = 0; j < 4; ++j) acc[i][j] = (f32x4){0.f, 0.f, 0.f, 0.f};

  for (int ks = 0; ks < C_ / 32; ++ks) {
#pragma unroll
    for (int j = 0; j < 2; ++j) {
      int row = wid * 16 + j * 64 + srow;
      gload_lds16(Y + (size_t)(m0 + row) * C_ + ks * 32 + scol,
                  &As[(wid * 16 + j * 64) * 32]);
      gload_lds16(WpT + (size_t)(n0 + row) * C_ + ks * 32 + scol,
                  &Bs[(wid * 16 + j * 64) * 32]);
    }
    __syncthreads();
    u16x8 af[4], bfr[4];
#pragma unroll
    for (int mi = 0; mi < 4; ++mi)
      af[mi] = *(const u16x8*)&As[(wm * 64 + mi * 16 + l15) * 32 + l4 * 8];
#pragma unroll
    for (int ni = 0; ni < 4; ++ni)
      bfr[ni] = *(const u16x8*)&Bs[(wn * 64 + ni * 16 + l15) * 32 + l4 * 8];
#pragma unroll
    for (int mi = 0; mi < 4; ++mi)
#pragma unroll
      for (int ni = 0; ni < 4; ++ni) acc[mi][ni] = mfma16(af[mi], bfr[ni], acc[mi][ni]);
    __syncthreads();
  }
#pragma unroll
  for (int mi = 0; mi < 4; ++mi)
#pragma unroll
    for (int ni = 0; ni < 4; ++ni)
#pragma unroll
      for (int rr = 0; rr < 4; ++rr) {
        int m = m0 + wm * 64 + mi * 16 + l4 * 4 + rr;
        int n = n0 + wn * 64 + ni * 16 + l15;
        __builtin_nontemporal_store(acc[mi][ni][rr] + bias[n],
                                    &out[(size_t)m * C_ + n]);
      }
}

extern "C" void kernel_launch(void* const* d_in, const int* in_sizes, int n_in,
                              void* d_out, int out_size, void* d_ws, size_t ws_size,
                              hipStream_t stream) {
  const float* x = (const float*)d_in[0];
  // d_in[1] = attention_mask (causal, replicated analytically)
  const float* W_attn = (const float*)d_in[2];
  const float* b_attn = (const float*)d_in[3];
  const float* W_proj = (const float*)d_in[4];
  const float* b_proj = (const float*)d_in[5];

  float* out_y = (float*)d_out;                       // [BT][C]
  float* out_att = (float*)d_out + (size_t)BT_ * C_;  // [B][H][T][T]

  unsigned short* WaT = (unsigned short*)d_ws;                 // [3072][1024] bf16
  unsigned short* WpT = WaT + (size_t)N3_ * C_;                // [1024][1024] bf16
  unsigned short* qkvb = WpT + (size_t)C_ * C_;                // Q,K [b][h][t][d]; V^T [b][h][d][t]
  unsigned short* Yb = qkvb + (size_t)3 * B_ * H_ * T_ * D_;   // [BT][C] bf16
  unsigned short* xb = Yb + (size_t)BT_ * C_;                  // [BT][C] bf16

  transpose_to_bf16T<<<dim3(N3_ / 32, C_ / 32), 256, 0, stream>>>(W_attn, WaT, C_, N3_);
  transpose_to_bf16T<<<dim3(C_ / 32, C_ / 32), 256, 0, stream>>>(W_proj, WpT, C_, C_);
  convert_x<<<dim3(BT_ * C_ / (256 * 8)), 256, 0, stream>>>(x, xb);
  gemm_qkv<<<dim3(N3_ / 128, BT_ / 128), 256, 0, stream>>>(xb, WaT, b_attn, qkvb);
  attn_kernel<<<dim3(NQT_ * H_ * B_), 512, 0, stream>>>(qkvb, out_att, Yb);
  gemm_proj<<<dim3(C_ / 128, BT_ / 128), 256, 0, stream>>>(Yb, WpT, b_proj, out_y);
}

// Round 20
// 283.119 us; speedup vs baseline: 1.0570x; 1.0570x over previous
//
#include <hip/hip_runtime.h>
#include <hip/hip_bf16.h>

#define B_ 2
#define T_ 2048
#define C_ 1024
#define H_ 16
#define D_ 64
#define BT_ (B_*T_)
#define N3_ (3*C_)
#define NKT_ (T_/64)     // 32 k-tiles of 64
#define NQT_ (T_/128)    // 16 q-tiles of 128

typedef float f32x4 __attribute__((ext_vector_type(4)));
typedef unsigned short u16x4 __attribute__((ext_vector_type(4)));
typedef unsigned short u16x8 __attribute__((ext_vector_type(8)));
typedef __bf16 bf16x8 __attribute__((ext_vector_type(8)));

// MFMA via intrinsic ONLY (raw inline-asm MFMA lacks compiler hazard waits ->
// schedule-dependent corruption, proven rounds 2/3/4/7/8 vs 9).
__device__ __forceinline__ f32x4 mfma16(u16x8 a, u16x8 b, f32x4 c) {
  union Cvt { u16x8 u; bf16x8 h; };
  Cvt ua, ub; ua.u = a; ub.u = b;
  return __builtin_amdgcn_mfma_f32_16x16x32_bf16(ua.h, ub.h, c, 0, 0, 0);
}

// raw v_exp_f32 (2^x).
__device__ __forceinline__ float exp2_fast(float x) {
  return __builtin_amdgcn_exp2f(x);
}

__device__ __forceinline__ unsigned short f2bf(float f) {
  union { float f; unsigned u; } v; v.f = f;
  unsigned r = v.u + 0x7FFFu + ((v.u >> 16) & 1u);
  return (unsigned short)(r >> 16);
}

__device__ __forceinline__ float bf2f(unsigned short u) {
  union { unsigned u; float f; } v; v.u = ((unsigned)u) << 16;
  return v.f;
}

// Non-temporal f32x4 store: att is a 537 MB write-once stream; bypass L2
// write-allocate so K/V working set stays resident (round 18: -27 us).
// NOTE (round 19 lesson): stores share vmcnt with loads — issue NT streams
// AFTER the dependent-load phases, never before (front-loading cost +15 us).
__device__ __forceinline__ void nt_store4(float* p, f32x4 v) {
  __builtin_nontemporal_store(v, (f32x4*)p);
}

__device__ __forceinline__ void gload_lds16(const unsigned short* g, unsigned short* l) {
  __builtin_amdgcn_global_load_lds(
      (const __attribute__((address_space(1))) unsigned int*)g,
      (__attribute__((address_space(3))) unsigned int*)l, 16, 0, 0);
}

// ---------------- transpose fp32 W[K][N] -> bf16 WT[N][K] ----------------
__global__ __launch_bounds__(256) void transpose_to_bf16T(
    const float* __restrict__ W, unsigned short* __restrict__ WT, int K, int N) {
  __shared__ float tile[32][33];
  int n0 = blockIdx.x * 32, k0 = blockIdx.y * 32;
  int tx = threadIdx.x & 31, ty = threadIdx.x >> 5;  // 32 x 8
#pragma unroll
  for (int i = 0; i < 4; ++i)
    tile[ty + i * 8][tx] = W[(size_t)(k0 + ty + i * 8) * N + n0 + tx];
  __syncthreads();
#pragma unroll
  for (int i = 0; i < 4; ++i)
    WT[(size_t)(n0 + ty + i * 8) * K + k0 + tx] = f2bf(tile[tx][ty + i * 8]);
}

// ---------------- convert x fp32 -> bf16 ----------------
__global__ __launch_bounds__(256) void convert_x(const float* __restrict__ x,
                                                 unsigned short* __restrict__ xb) {
  int i = (blockIdx.x * 256 + threadIdx.x) * 8;
  f32x4 a = *(const f32x4*)(x + i);
  f32x4 b = *(const f32x4*)(x + i + 4);
  u16x8 o;
  o[0]=f2bf(a[0]); o[1]=f2bf(a[1]); o[2]=f2bf(a[2]); o[3]=f2bf(a[3]);
  o[4]=f2bf(b[0]); o[5]=f2bf(b[1]); o[6]=f2bf(b[2]); o[7]=f2bf(b[3]);
  *(u16x8*)(xb + i) = o;
}

// ---------------- GEMM1: qkv = xb @ WaT^T + b_attn -> bf16 Q/K (row) + V^T ----------------
__global__ __launch_bounds__(256) void gemm_qkv(
    const unsigned short* __restrict__ xb, const unsigned short* __restrict__ WaT,
    const float* __restrict__ bias, unsigned short* __restrict__ qkv) {
  __shared__ __attribute__((aligned(16))) unsigned short As[128 * 32];
  __shared__ __attribute__((aligned(16))) unsigned short Bs[128 * 32];
  int n0 = blockIdx.x * 128;
  int m0 = blockIdx.y * 128;
  int tid = threadIdx.x;
  int lane = tid & 63, wid = tid >> 6;
  int wm = wid >> 1, wn = wid & 1;
  int l15 = lane & 15, l4 = lane >> 4;
  int srow = lane >> 2, scol = (lane & 3) << 3;

  f32x4 acc[4][4];
#pragma unroll
  for (int i = 0; i < 4; ++i)
#pragma unroll
    for (int j = 0; j < 4; ++j) acc[i][j] = (f32x4){0.f, 0.f, 0.f, 0.f};

  for (int ks = 0; ks < C_ / 32; ++ks) {
#pragma unroll
    for (int j = 0; j < 2; ++j) {
      int row = wid * 16 + j * 64 + srow;
      gload_lds16(xb + (size_t)(m0 + row) * C_ + ks * 32 + scol,
                  &As[(wid * 16 + j * 64) * 32]);
      gload_lds16(WaT + (size_t)(n0 + row) * C_ + ks * 32 + scol,
                  &Bs[(wid * 16 + j * 64) * 32]);
    }
    __syncthreads();
    u16x8 af[4], bfr[4];
#pragma unroll
    for (int mi = 0; mi < 4; ++mi)
      af[mi] = *(const u16x8*)&As[(wm * 64 + mi * 16 + l15) * 32 + l4 * 8];
#pragma unroll
    for (int ni = 0; ni < 4; ++ni)
      bfr[ni] = *(const u16x8*)&Bs[(wn * 64 + ni * 16 + l15) * 32 + l4 * 8];
#pragma unroll
    for (int mi = 0; mi < 4; ++mi)
#pragma unroll
      for (int ni = 0; ni < 4; ++ni) acc[mi][ni] = mfma16(af[mi], bfr[ni], acc[mi][ni]);
    __syncthreads();
  }

  if (n0 < 2 * C_) {
    // Q/K: [sect][b][h][t][d]; Q pre-scaled by 0.125*log2e (exp2 softmax)
    float qscale = (n0 < C_) ? 0.125f * 1.44269504f : 1.0f;
#pragma unroll
    for (int mi = 0; mi < 4; ++mi)
#pragma unroll
      for (int ni = 0; ni < 4; ++ni)
#pragma unroll
        for (int rr = 0; rr < 4; ++rr) {
          int m = m0 + wm * 64 + mi * 16 + l4 * 4 + rr;
          int n = n0 + wn * 64 + ni * 16 + l15;
          float v = (acc[mi][ni][rr] + bias[n]) * qscale;
          int b = m >> 11, tok = m & (T_ - 1);
          int sect = n >> 10, h = (n >> 6) & 15, d = n & 63;
          size_t idx = ((((size_t)sect * B_ + b) * H_ + h) * T_ + tok) * D_ + d;
          qkv[idx] = f2bf(v);
        }
  } else {
    // V -> [b][h][d][t]: 4 consecutive tokens per lane -> u16x4 direct store.
    unsigned short* vbase = qkv + (size_t)2 * B_ * H_ * T_ * D_;
    int m_b = m0 >> 11;
#pragma unroll
    for (int mi = 0; mi < 4; ++mi) {
      int m = m0 + wm * 64 + mi * 16 + l4 * 4;   // first of 4 consecutive tokens
      int tok = m & (T_ - 1);
#pragma unroll
      for (int ni = 0; ni < 4; ++ni) {
        int n = n0 + wn * 64 + ni * 16 + l15;
        float bi = bias[n];
        int h = (n >> 6) & 15, d = n & 63;
        u16x4 val;
        val[0] = f2bf(acc[mi][ni][0] + bi);
        val[1] = f2bf(acc[mi][ni][1] + bi);
        val[2] = f2bf(acc[mi][ni][2] + bi);
        val[3] = f2bf(acc[mi][ni][3] + bi);
        *(u16x4*)&vbase[(((size_t)m_b * H_ + h) * D_ + d) * T_ + tok] = val;
      }
    }
  }
}

// ---------------- fused causal attention, QBLK=128 (8 waves), NT att stores ----------------
// Round-18 proven layout: zero-fill at TAIL (after load phases; vmcnt lesson).
__global__ __launch_bounds__(512) void attn_kernel(
    const unsigned short* __restrict__ qkv, float* __restrict__ att,
    unsigned short* __restrict__ Y) {
  int idx = blockIdx.x;
  int qt = NQT_ - 1 - (idx >> 5);   // descending: big blocks dispatch first
  int hb = idx & 31;
  int h = hb & 15;
  int b = hb >> 4;
  int q0 = qt * 128;
  int nkt = 2 * qt + 2;             // k-tiles covering rows q0..q0+127
  int tid = threadIdx.x, lane = tid & 63, wid = tid >> 6;   // wid 0..7
  int l15 = lane & 15, l4 = lane >> 4;
  int rowbase = q0 + wid * 16;

  const unsigned short* Q = qkv + (((size_t)(0 * B_ + b) * H_ + h) * T_) * D_;
  const unsigned short* K = qkv + (((size_t)(1 * B_ + b) * H_ + h) * T_) * D_;
  const unsigned short* VtG = qkv + (size_t)2 * B_ * H_ * T_ * D_ +
                              (((size_t)b * H_ + h) * D_) * T_;
  float* attbase = att + ((size_t)(b * H_ + h) * T_) * T_;

  __shared__ __attribute__((aligned(16))) unsigned short Ps[2][128][72];
  __shared__ __attribute__((aligned(16))) unsigned short Vt[2][64][72];

  // Q fragments (this wave owns rows rowbase .. rowbase+15)
  u16x8 qf[2];
#pragma unroll
  for (int c = 0; c < 2; ++c)
    qf[c] = *(const u16x8*)(Q + (size_t)(rowbase + l15) * D_ + c * 32 + l4 * 8);

  int myrow[4];
#pragma unroll
  for (int rr = 0; rr < 4; ++rr) myrow[rr] = rowbase + l4 * 4 + rr;

  // ---- pass 1: per-lane partial row sums ----
  float esum[4] = {0.f, 0.f, 0.f, 0.f};
  for (int kt = 0; kt < nkt; ++kt) {
    int k0 = kt * 64;
    if (k0 > rowbase + 15) continue;  // fully masked for this wave (uniform)
    f32x4 s[4];
#pragma unroll
    for (int g = 0; g < 4; ++g) s[g] = (f32x4){0.f, 0.f, 0.f, 0.f};
#pragma unroll
    for (int g = 0; g < 4; ++g)
#pragma unroll
      for (int c = 0; c < 2; ++c) {
        u16x8 kf = *(const u16x8*)(K + (size_t)(k0 + g * 16 + l15) * D_ + c * 32 + l4 * 8);
        s[g] = mfma16(qf[c], kf, s[g]);
      }
    if (k0 + 63 <= rowbase) {  // fully visible (uniform)
#pragma unroll
      for (int g = 0; g < 4; ++g)
#pragma unroll
        for (int rr = 0; rr < 4; ++rr) esum[rr] += exp2_fast(s[g][rr]);
    } else {                   // diagonal
#pragma unroll
      for (int g = 0; g < 4; ++g) {
        int col = k0 + g * 16 + l15;
#pragma unroll
        for (int rr = 0; rr < 4; ++rr)
          esum[rr] += (col > myrow[rr]) ? 0.f : exp2_fast(s[g][rr]);
      }
    }
  }
  float inv_l[4];
#pragma unroll
  for (int rr = 0; rr < 4; ++rr) {
    float e = esum[rr];
    e += __shfl_xor(e, 1);
    e += __shfl_xor(e, 2);
    e += __shfl_xor(e, 4);
    e += __shfl_xor(e, 8);
    inv_l[rr] = 1.f / e;
  }

  // ---- pass 2: accumulate PV; att written NT from Ps; 1 barrier/tile via dbuf ----
  f32x4 yacc[4];
#pragma unroll
  for (int g = 0; g < 4; ++g) yacc[g] = (f32x4){0.f, 0.f, 0.f, 0.f};

  for (int kt = 0; kt < nkt; ++kt) {
    int k0 = kt * 64;
    int p = kt & 1;
    bool wave_masked = (k0 > rowbase + 15);
    // stage V^T tile into buf p (512 threads x u16x8 = 8 KB tile)
    {
      int dd = tid >> 3;
      int kq = (tid & 7) * 8;
      *(u16x8*)&Vt[p][dd][kq] = *(const u16x8*)(VtG + (size_t)dd * T_ + k0 + kq);
    }
    if (wave_masked) {
      // all p = 0 for this wave's rows: zero Ps, att zeros via readback
#pragma unroll
      for (int g = 0; g < 4; ++g)
#pragma unroll
        for (int rr = 0; rr < 4; ++rr)
          Ps[p][wid * 16 + l4 * 4 + rr][g * 16 + l15] = 0;
    } else {
      f32x4 s[4];
#pragma unroll
      for (int g = 0; g < 4; ++g) s[g] = (f32x4){0.f, 0.f, 0.f, 0.f};
#pragma unroll
      for (int g = 0; g < 4; ++g)
#pragma unroll
        for (int c = 0; c < 2; ++c) {
          u16x8 kf = *(const u16x8*)(K + (size_t)(k0 + g * 16 + l15) * D_ + c * 32 + l4 * 8);
          s[g] = mfma16(qf[c], kf, s[g]);
        }
      if (k0 + 63 <= rowbase) {
#pragma unroll
        for (int g = 0; g < 4; ++g)
#pragma unroll
          for (int rr = 0; rr < 4; ++rr)
            Ps[p][wid * 16 + l4 * 4 + rr][g * 16 + l15] =
                f2bf(exp2_fast(s[g][rr]) * inv_l[rr]);
      } else {
#pragma unroll
        for (int g = 0; g < 4; ++g) {
          int col = k0 + g * 16 + l15;
#pragma unroll
          for (int rr = 0; rr < 4; ++rr) {
            float pv = (col > myrow[rr]) ? 0.f : exp2_fast(s[g][rr]) * inv_l[rr];
            Ps[p][wid * 16 + l4 * 4 + rr][g * 16 + l15] = f2bf(pv);
          }
        }
      }
    }
    // att write: read own-wave Ps rows back vectorized; NT store (streamed).
    {
      int cc = l15 * 4;
#pragma unroll
      for (int jj = 0; jj < 4; ++jj) {
        int rrow = wid * 16 + jj * 4 + l4;
        const unsigned short* ps = &Ps[p][rrow][cc];
        f32x4 o;
        o[0] = bf2f(ps[0]); o[1] = bf2f(ps[1]);
        o[2] = bf2f(ps[2]); o[3] = bf2f(ps[3]);
        nt_store4(&attbase[(size_t)(q0 + rrow) * T_ + k0 + cc], o);
      }
    }
    __syncthreads();  // buf p fully written by all waves
    // PV from buf p (skip when this wave's P-rows are all zero)
    if (!wave_masked) {
#pragma unroll
      for (int c = 0; c < 2; ++c) {
        u16x8 pf = *(const u16x8*)&Ps[p][wid * 16 + l15][c * 32 + l4 * 8];
#pragma unroll
        for (int g = 0; g < 4; ++g) {
          u16x8 vf = *(const u16x8*)&Vt[p][g * 16 + l15][c * 32 + l4 * 8];
          yacc[g] = mfma16(pf, vf, yacc[g]);
        }
      }
    }
  }

  // zero the fully-masked upper tiles (NT streamed, 256B-contiguous per row)
  f32x4 z = (f32x4){0.f, 0.f, 0.f, 0.f};
  for (int kt = nkt; kt < NKT_; ++kt) {
    int k0 = kt * 64;
#pragma unroll
    for (int rr = 0; rr < 4; ++rr)
      nt_store4(&attbase[(size_t)myrow[rr] * T_ + k0 + l15 * 4], z);
  }

  // write Y bf16 [BT][C]
#pragma unroll
  for (int g = 0; g < 4; ++g)
#pragma unroll
    for (int rr = 0; rr < 4; ++rr)
      Y[(size_t)(b * T_ + myrow[rr]) * C_ + h * D_ + g * 16 + l15] = f2bf(yacc[g][rr]);
}

// ---------------- GEMM2: out = Y @ W_proj + b_proj (fp32 out, NT epilogue) ----------------
__global__ __launch_bounds__(256) void gemm_proj(
    const unsigned short* __restrict__ Y, const unsigned short* __restrict__ WpT,
    const float* __restrict__ bias, float* __restrict__ out) {
  __shared__ __attribute__((aligned(16))) unsigned short As[128 * 32];
  __shared__ __attribute__((aligned(16))) unsigned short Bs[128 * 32];
  int n0 = blockIdx.x * 128;
  int m0 = blockIdx.y * 128;
  int tid = threadIdx.x;
  int lane = tid & 63, wid = tid >> 6;
  int wm = wid >> 1, wn = wid & 1;
  int l15 = lane & 15, l4 = lane >> 4;
  int srow = lane >> 2, scol = (lane & 3) << 3;

  f32x4 acc[4][4];
#pragma unroll
  for (int i = 0; i < 4; ++i)
#pragma unroll
    for (int j = 0; j < 4; ++j) acc[i][j] = (f32x4){0.f, 0.f, 0.f, 0.f};

  for (int ks = 0; ks < C_ / 32; ++ks) {
#pragma unroll
    for (int j = 0; j < 2; ++j) {
      int row = wid * 16 + j * 64 + srow;
      gload_lds16(Y + (size_t)(m0 + row) * C_ + ks * 32 + scol,
                  &As[(wid * 16 + j * 64) * 32]);
      gload_lds16(WpT + (size_t)(n0 + row) * C_ + ks * 32 + scol,
                  &Bs[(wid * 16 + j * 64) * 32]);
    }
    __syncthreads();
    u16x8 af[4], bfr[4];
#pragma unroll
    for (int mi = 0; mi < 4; ++mi)
      af[mi] = *(const u16x8*)&As[(wm * 64 + mi * 16 + l15) * 32 + l4 * 8];
#pragma unroll
    for (int ni = 0; ni < 4; ++ni)
      bfr[ni] = *(const u16x8*)&Bs[(wn * 64 + ni * 16 + l15) * 32 + l4 * 8];
#pragma unroll
    for (int mi = 0; mi < 4; ++mi)
#pragma unroll
      for (int ni = 0; ni < 4; ++ni) acc[mi][ni] = mfma16(af[mi], bfr[ni], acc[mi][ni]);
    __syncthreads();
  }
#pragma unroll
  for (int mi = 0; mi < 4; ++mi)
#pragma unroll
    for (int ni = 0; ni < 4; ++ni)
#pragma unroll
      for (int rr = 0; rr < 4; ++rr) {
        int m = m0 + wm * 64 + mi * 16 + l4 * 4 + rr;
        int n = n0 + wn * 64 + ni * 16 + l15;
        __builtin_nontemporal_store(acc[mi][ni][rr] + bias[n],
                                    &out[(size_t)m * C_ + n]);
      }
}

extern "C" void kernel_launch(void* const* d_in, const int* in_sizes, int n_in,
                              void* d_out, int out_size, void* d_ws, size_t ws_size,
                              hipStream_t stream) {
  const float* x = (const float*)d_in[0];
  // d_in[1] = attention_mask (causal, replicated analytically)
  const float* W_attn = (const float*)d_in[2];
  const float* b_attn = (const float*)d_in[3];
  const float* W_proj = (const float*)d_in[4];
  const float* b_proj = (const float*)d_in[5];

  float* out_y = (float*)d_out;                       // [BT][C]
  float* out_att = (float*)d_out + (size_t)BT_ * C_;  // [B][H][T][T]

  unsigned short* WaT = (unsigned short*)d_ws;                 // [3072][1024] bf16
  unsigned short* WpT = WaT + (size_t)N3_ * C_;                // [1024][1024] bf16
  unsigned short* qkvb = WpT + (size_t)C_ * C_;                // Q,K [b][h][t][d]; V^T [b][h][d][t]
  unsigned short* Yb = qkvb + (size_t)3 * B_ * H_ * T_ * D_;   // [BT][C] bf16
  unsigned short* xb = Yb + (size_t)BT_ * C_;                  // [BT][C] bf16

  transpose_to_bf16T<<<dim3(N3_ / 32, C_ / 32), 256, 0, stream>>>(W_attn, WaT, C_, N3_);
  transpose_to_bf16T<<<dim3(C_ / 32, C_ / 32), 256, 0, stream>>>(W_proj, WpT, C_, C_);
  convert_x<<<dim3(BT_ * C_ / (256 * 8)), 256, 0, stream>>>(x, xb);
  gemm_qkv<<<dim3(N3_ / 128, BT_ / 128), 256, 0, stream>>>(xb, WaT, b_attn, qkvb);
  attn_kernel<<<dim3(NQT_ * H_ * B_), 512, 0, stream>>>(qkvb, out_att, Yb);
  gemm_proj<<<dim3(C_ / 128, BT_ / 128), 256, 0, stream>>>(Yb, WpT, b_proj, out_y);
}